// Round 7
// baseline (297.801 us; speedup 1.0000x reference)
//
#include <hip/hip_runtime.h>
#include <cmath>

// ---------------------------------------------------------------------------
// Bit-exact replication of the reference's f32 cumsum TREE (JAX associative
// scan), validated rounds 5/6 (absmax 1.831e-3 both). Round 6 post-mortem:
// k_synth2's per-lane parity divergence made every wave execute ALL
// reconstruction branches (~220 instr/iter vs ~70), plus 2 barriers + 544
// shared-inc recomputes per k, plus 77M IEEE divides in k_scan4.
// This round: 16 consecutive j per thread -> uniform straight-line
// reconstruction from scan4[q-1]/scan4[q]; no barriers in the k-loop;
// k-split x4 over grid.z; exact constant-division + mod-2pi via f32
// double-float fma transforms (proved correctly-rounded: no halfway cases,
// err 2^-47 << 2^-33.5 boundary distance).
// ---------------------------------------------------------------------------
#pragma clang fp contract(off)

#define SRF   48000.0f
#define NYQF  21600.0f                    // fp32(48000*0.45), exact
constexpr float  TWO_PI_F  = 6.283185307179586476925286766559f;  // 0x40C90FDB
constexpr double INV_2PI_D = 0.15915494309189533576888376337251;
constexpr float  RC1 = (float)INV_2PI_D;
constexpr float  RC2 = (float)(INV_2PI_D - (double)RC1);
constexpr double INV_SR_D = 1.0 / 48000.0;
constexpr float  DD1 = (float)INV_SR_D;
constexpr float  DD2 = (float)(INV_SR_D - (double)DD1);

__device__ __forceinline__ float hsin_rev(float r) {  // sin(2*pi*r)
#if __has_builtin(__builtin_amdgcn_sinf)
    return __builtin_amdgcn_sinf(r);                  // v_sin_f32: revolutions
#else
    return __sinf(r * TWO_PI_F);
#endif
}

// Correctly-rounded t/48000 via double-float mul (== IEEE f32 divide here).
__device__ __forceinline__ float div48000(float t) {
    float h = t * DD1;
    float r = __builtin_fmaf(t, DD1, -h);   // exact residual of t*DD1
    float s = __builtin_fmaf(t, DD2, r);
    return h + s;
}

// sin(ph) for f32 ph (|ph| <= ~2e5 rad): double-float reduction to
// revolutions, |fr err| <= ~2^-25 rev, then hardware sin.
__device__ __forceinline__ float sin_phase(float ph) {
    float h  = ph * RC1;
    float r  = __builtin_fmaf(ph, RC1, -h);
    float s  = __builtin_fmaf(ph, RC2, r);
    float nn = __builtin_rintf(h);          // v_rndne_f32
    float fr = (h - nn) + s;                // (h-nn) exact (Sterbenz)
    return hsin_rev(fr);
}

// kc[b,k] = fp32(k * fp32(sqrt(fp32(1 + fp32(inh*k^2)))))  -- np/jnp-exact
__device__ __forceinline__ float kcval(int k, float ib) {
    float kf = (float)(k + 1);
    float k2 = kf * kf;
    float m  = ib * k2;
    float s1 = 1.0f + m;
    float st = (float)sqrt((double)s1);     // correctly-rounded f32 sqrt
    return kf * st;
}

// ---- K1: f0_up[b,j], np-exact fp32 linear interp ---------------------------
__global__ void __launch_bounds__(256) k_f0up(const float* __restrict__ f0,
        float* __restrict__ f0up, int T, int n, float pf) {
    int j = blockIdx.x * 256 + threadIdx.x;
    int b = blockIdx.y;
    if (j >= n) return;
    float pos = ((float)j + 0.5f);
    pos = pos * pf;
    pos = pos - 0.5f;
    pos = fmaxf(pos, 0.0f);
    pos = fminf(pos, (float)(T - 1));
    int   i0 = (int)pos;
    int   i1 = min(i0 + 1, T - 1);
    float w  = pos - (float)i0;
    float omw = 1.0f - w;
    const float* fb = f0 + b * T;
    f0up[(size_t)b * n + j] = fb[i0] * omw + fb[i1] * w;
}

// ---- K2a: per (b,k) produce scan4 (level-4 inclusive tree scan) ------------
__global__ void __launch_bounds__(256) k_scan4(const float* __restrict__ f0up,
        const float* __restrict__ inh, float* __restrict__ scan4,
        int N, int n) {
    __shared__ float lv[6016];
    const int k   = blockIdx.x;
    const int b   = blockIdx.y;
    const int tid = threadIdx.x;
    const float kc = kcval(k, inh[b]);
    const float4* f4 = (const float4*)(f0up + (size_t)b * n);

    int len[28], off[28];
    len[4] = n >> 4;
    int P = 4;
    for (int l = 5; l < 28; ++l) { len[l] = len[l-1] >> 1; P = l; if (len[l] == 1) break; }
    off[4] = 0;
    for (int l = 5; l <= P; ++l) off[l] = off[l-1] + len[l-1];

    for (int i = tid; i < len[4]; i += 256) {
        float4 u0 = f4[4*i], u1 = f4[4*i+1], u2 = f4[4*i+2], u3 = f4[4*i+3];
        float a0=div48000(TWO_PI_F*(kc*u0.x)), a1=div48000(TWO_PI_F*(kc*u0.y));
        float a2=div48000(TWO_PI_F*(kc*u0.z)), a3=div48000(TWO_PI_F*(kc*u0.w));
        float a4=div48000(TWO_PI_F*(kc*u1.x)), a5=div48000(TWO_PI_F*(kc*u1.y));
        float a6=div48000(TWO_PI_F*(kc*u1.z)), a7=div48000(TWO_PI_F*(kc*u1.w));
        float a8=div48000(TWO_PI_F*(kc*u2.x)), a9=div48000(TWO_PI_F*(kc*u2.y));
        float aA=div48000(TWO_PI_F*(kc*u2.z)), aB=div48000(TWO_PI_F*(kc*u2.w));
        float aC=div48000(TWO_PI_F*(kc*u3.x)), aD=div48000(TWO_PI_F*(kc*u3.y));
        float aE=div48000(TWO_PI_F*(kc*u3.z)), aF=div48000(TWO_PI_F*(kc*u3.w));
        float L2a=(a0+a1)+(a2+a3), L2b=(a4+a5)+(a6+a7);
        float L2c=(a8+a9)+(aA+aB), L2d=(aC+aD)+(aE+aF);
        lv[i] = (L2a+L2b) + (L2c+L2d);
    }
    __syncthreads();
    for (int l = 5; l <= P; ++l) {
        const float* src = lv + off[l-1];
        float*       dst = lv + off[l];
        for (int i = tid; i < len[l]; i += 256) dst[i] = src[2*i] + src[2*i+1];
        __syncthreads();
    }
    for (int l = P - 1; l >= 4; --l) {
        float*       arr = lv + off[l];
        const float* hi  = lv + off[l+1];
        for (int i = tid; i < len[l+1]; i += 256) {
            float v = hi[i];
            int e = 2*i + 2;
            if (e < len[l]) arr[e] = v + arr[e];
            arr[2*i + 1] = v;
        }
        __syncthreads();
    }
    float* sp = scan4 + (size_t)(b * N + k) * len[4];
    for (int i = tid; i < len[4]; i += 256) sp[i] = lv[i];
}

// ---- K2b: 16 consecutive j per thread, uniform reconstruction from scan4 ---
#define ROWS 26
__global__ void __launch_bounds__(256) k_synth3(
        const float* __restrict__ harm, const float* __restrict__ f0up,
        const float* __restrict__ inh,  const float* __restrict__ scan4,
        float* __restrict__ out, int B, int T, int N, int n, float pf, int kpg) {
    const int tid  = threadIdx.x;
    const int b    = blockIdx.y;
    const int k0   = blockIdx.z * kpg;
    const int q    = blockIdx.x * 256 + tid;      // 16-sample group id
    const int NG   = n >> 4;
    const int kend = min(k0 + kpg, N);
    const int kact = kend - k0;

    __shared__ float amps[ROWS * 32];             // [row][kk], stride kact
    __shared__ float kcs[32];
    __shared__ float red[256];

    const float ib    = inh[b];
    const float tmaxf = (float)(T - 1);

    for (int i = tid; i < kact; i += 256) kcs[i] = kcval(k0 + i, ib);

    // block-common base row
    const int j0blk = blockIdx.x * 4096;
    int i0min;
    {
        float p = ((float)j0blk + 0.5f);
        p = p * pf; p = p - 0.5f;
        p = fmaxf(p, 0.0f); p = fminf(p, tmaxf);
        i0min = (int)p;
    }
    for (int idx = tid; idx < ROWS * kact; idx += 256) {
        int r = idx / kact, kk = idx - r * kact;
        int row = min(i0min + r, T - 1);
        amps[r * kact + kk] = harm[((size_t)b * T + row) * N + (k0 + kk)];
    }

    // per-thread u[16] + geometry
    float u[16];
    float w[16];
    int   ao[16];
    float um = __builtin_inff();
    if (q < NG) {
        const float4* up = (const float4*)(f0up + (size_t)b * n + (size_t)q * 16);
        float4 v0 = up[0], v1 = up[1], v2 = up[2], v3 = up[3];
        u[0]=v0.x; u[1]=v0.y; u[2]=v0.z; u[3]=v0.w;
        u[4]=v1.x; u[5]=v1.y; u[6]=v1.z; u[7]=v1.w;
        u[8]=v2.x; u[9]=v2.y; u[10]=v2.z; u[11]=v2.w;
        u[12]=v3.x; u[13]=v3.y; u[14]=v3.z; u[15]=v3.w;
        #pragma unroll
        for (int i = 0; i < 16; ++i) {
            um = fminf(um, u[i]);
            int j = q * 16 + i;
            float p = ((float)j + 0.5f);
            p = p * pf; p = p - 0.5f;
            p = fmaxf(p, 0.0f); p = fminf(p, tmaxf);
            int i0 = (int)p;
            w[i]  = p - (float)i0;
            ao[i] = (i0 - i0min) * kact;
        }
    }
    red[tid] = um;
    __syncthreads();
    for (int s = 128; s > 0; s >>= 1) {
        if (tid < s) red[tid] = fminf(red[tid], red[tid + s]);
        __syncthreads();
    }
    const float umin = red[0];

    if (q < NG) {
        float acc[16];
        #pragma unroll
        for (int i = 0; i < 16; ++i) acc[i] = 0.0f;

        const float* s4b = scan4 + (size_t)(b * N + k0) * NG;

        for (int k = k0; k < kend; ++k) {
            const int   kk = k - k0;
            const float kc = kcs[kk];
            if (kc * umin >= NYQF) break;         // uniform: kc monotone in k
            const float* s4k = s4b + (size_t)kk * NG;
            float g0 = (q == 0) ? 0.0f : s4k[q - 1];
            float g1 = s4k[q];

            // bit-exact increments (ref: fp32(fp32(2pi*fp32(kc*u))/48000))
            float x[16];
            #pragma unroll
            for (int i = 0; i < 16; ++i)
                x[i] = div48000(TWO_PI_F * (kc * u[i]));

            // tree partials (round-5-validated associations)
            float L1a = x[0]+x[1],   L1b = x[2]+x[3];
            float L1c = x[4]+x[5],   L1d = x[6]+x[7];
            float L1e = x[8]+x[9],   L1f = x[10]+x[11];
            float L1g = x[12]+x[13];
            float L2a = L1a+L1b, L2b = L1c+L1d, L2c = L1e+L1f;
            float L3a = L2a+L2b;
            float p0  = g0 + x[0];
            float s10 = g0 + L1a;
            float p2  = s10 + x[2];
            float s20 = g0 + L2a;
            float p4  = s20 + x[4];
            float s12 = s20 + L1c;
            float p6  = s12 + x[6];
            float s3v = g0 + L3a;
            float p8  = s3v + x[8];
            float s14 = s3v + L1e;
            float p10 = s14 + x[10];
            float s22 = s3v + L2c;
            float p12 = s22 + x[12];
            float s16 = s22 + L1g;
            float p14 = s16 + x[14];

            auto emit = [&](int i, float ph) {
                float t1 = kc * u[i];             // same RN product as ref mask
                if (t1 < NYQF) {
                    float sv = sin_phase(ph);
                    int idx  = ao[i] + kk;
                    float a0 = amps[idx];
                    float a1 = amps[idx + kact];
                    float wv = w[i];
                    float a  = a0 * (1.0f - wv) + a1 * wv;
                    acc[i] += a * sv;
                }
            };
            emit(0, p0);   emit(1, s10); emit(2, p2);   emit(3, s20);
            emit(4, p4);   emit(5, s12); emit(6, p6);   emit(7, s3v);
            emit(8, p8);   emit(9, s14); emit(10, p10); emit(11, s22);
            emit(12, p12); emit(13, s16); emit(14, p14); emit(15, g1);
        }

        const float Nf = (float)N;
        float* ob = out + (size_t)b * n + (size_t)q * 16;
        #pragma unroll
        for (int i = 0; i < 16; ++i) atomicAdd(&ob[i], acc[i] / Nf);
    }
}

// ---- Fallback: round-5 proven kernel (atomics, 96 KB LDS) ------------------
__global__ void __launch_bounds__(256) k_scan_synth(
        const float* __restrict__ harm, const float* __restrict__ f0up,
        const float* __restrict__ inh,  float* __restrict__ out,
        int B, int T, int N, int n, float pf) {
    extern __shared__ float lv[];
    const int k   = blockIdx.x;
    const int b   = blockIdx.y;
    const int tid = threadIdx.x;
    const float kc = kcval(k, inh[b]);
    const float* fb = f0up + (size_t)b * n;
    constexpr double INV_2PI = INV_2PI_D * 1.0;

    auto inc = [&](int j) -> float {
        float u    = fb[j];
        float inst = kc * u;
        float tt   = TWO_PI_F * inst;
        return tt / SRF;
    };

    int len[24], off[24];
    len[1] = n >> 1;
    int P = 1;
    for (int l = 2; l < 24; ++l) { len[l] = len[l-1] >> 1; P = l; if (len[l] == 1) break; }
    off[2] = 0;
    for (int l = 3; l <= P; ++l) off[l] = off[l-1] + len[l-1];

    {
        const float4* f4 = (const float4*)fb;
        float* L2 = lv + off[2];
        for (int i = tid; i < len[2]; i += 256) {
            float4 u = f4[i];
            float a0 = (TWO_PI_F * (kc * u.x)) / SRF;
            float a1 = (TWO_PI_F * (kc * u.y)) / SRF;
            float a2 = (TWO_PI_F * (kc * u.z)) / SRF;
            float a3 = (TWO_PI_F * (kc * u.w)) / SRF;
            L2[i] = (a0 + a1) + (a2 + a3);
        }
    }
    __syncthreads();
    for (int l = 3; l <= P; ++l) {
        const float* src = lv + off[l-1];
        float*       dst = lv + off[l];
        for (int i = tid; i < len[l]; i += 256) dst[i] = src[2*i] + src[2*i+1];
        __syncthreads();
    }
    for (int l = P - 1; l >= 2; --l) {
        float*       arr = lv + off[l];
        const float* hi  = lv + off[l+1];
        for (int i = tid; i < len[l+1]; i += 256) {
            float v = hi[i];
            int e = 2*i + 2;
            if (e < len[l]) arr[e] = v + arr[e];
            arr[2*i + 1] = v;
        }
        __syncthreads();
    }
    const float* scan2 = lv + off[2];

    const float  tmaxf = (float)(T - 1);
    const float  invN  = 1.0f / (float)N;
    const float* hb    = harm + (size_t)b * T * N + k;
    float*       ob    = out + (size_t)b * n;

    auto emit = [&](int j, float ph) {
        float u    = fb[j];
        float inst = kc * u;
        if (!(inst < NYQF)) return;
        double pr = (double)ph * INV_2PI;
        double fr = pr - rint(pr);
        float  sv = hsin_rev((float)fr);
        float pos = ((float)j + 0.5f);
        pos = pos * pf; pos = pos - 0.5f;
        pos = fmaxf(pos, 0.0f); pos = fminf(pos, tmaxf);
        int   i0 = (int)pos;
        int   i1 = min(i0 + 1, T - 1);
        float w  = pos - (float)i0;
        float a  = hb[(size_t)i0 * N] * (1.0f - w) + hb[(size_t)i1 * N] * w;
        atomicAdd(&ob[j], (a * sv) * invN);
    };

    if (tid == 0) emit(0, inc(0));
    const int Hh = n >> 1;
    for (int tt = tid; tt < Hh; tt += 256) {
        float s1;
        if (tt == 0)      s1 = inc(0) + inc(1);
        else if (tt & 1)  s1 = scan2[(tt - 1) >> 1];
        else              s1 = scan2[(tt >> 1) - 1] + (inc(2*tt) + inc(2*tt + 1));
        emit(2*tt + 1, s1);
        int je = 2*tt + 2;
        if (je < n) emit(je, s1 + inc(je));
    }
}

extern "C" void kernel_launch(void* const* d_in, const int* in_sizes, int n_in,
                              void* d_out, int out_size, void* d_ws, size_t ws_size,
                              hipStream_t stream) {
    const int B = in_sizes[2];                 // 16
    const int T = in_sizes[1] / B;             // 250
    const int N = in_sizes[0] / (B * T);       // 100
    const int n = out_size / B;                // 48000
    const float pf = (float)((double)T / (double)n);

    const float* harm = (const float*)d_in[0];
    const float* f0   = (const float*)d_in[1];
    const float* inh  = (const float*)d_in[2];
    float* out  = (float*)d_out;
    float* f0up = (float*)d_ws;                // B*n floats = 3.07 MB

    const int KZ  = 4;
    const int kpg = (N + KZ - 1) / KZ;         // 25
    const size_t needFast = (size_t)B * n * 4 + (size_t)B * N * (n / 16) * 4;
    const bool fast = (ws_size >= needFast) && (n % 16 == 0) && (kpg <= 32);

    k_f0up<<<dim3((n + 255) / 256, B), 256, 0, stream>>>(f0, f0up, T, n, pf);
    hipMemsetAsync(d_out, 0, (size_t)out_size * sizeof(float), stream);

    if (fast) {
        float* scan4 = (float*)((char*)d_ws + (size_t)B * n * 4);
        k_scan4<<<dim3(N, B), 256, 0, stream>>>(f0up, inh, scan4, N, n);
        const int NG    = n / 16;                          // 3000
        const int tiles = (NG + 255) / 256;                // 12
        k_synth3<<<dim3(tiles, B, KZ), 256, 0, stream>>>(
            harm, f0up, inh, scan4, out, B, T, N, n, pf, kpg);
    } else {
        const size_t lds_bytes = (size_t)(n / 2) * sizeof(float);  // 96 KB
        k_scan_synth<<<dim3(N, B), 256, lds_bytes, stream>>>(
            harm, f0up, inh, out, B, T, N, n, pf);
    }
}

// Round 8
// 289.063 us; speedup vs baseline: 1.0302x; 1.0302x over previous
//
#include <hip/hip_runtime.h>
#include <cmath>

// ---------------------------------------------------------------------------
// Bit-exact replication of the reference's f32 cumsum TREE (JAX associative
// scan), validated rounds 5/6/7 (absmax 1.831e-3 all). Round 7 post-mortem:
// VGPR_Count=60 vs a 64+ register live set => the per-thread arrays spilled
// to scratch; every emit hit scratch-memory latency (VALUBusy 22%, 206 us).
// This round: __launch_bounds__(256,4) (128-VGPR budget, arrays stay in
// registers), next-k g0/g1 prefetch, per-wave umin break (shfl, no barriers),
// float2 amp pairs (one ds_read_b64/emit), and k_scan4 without dynamically
// indexed len/off arrays + prefetched float4 loads. Arithmetic dag unchanged.
// ---------------------------------------------------------------------------
#pragma clang fp contract(off)

#define SRF   48000.0f
#define NYQF  21600.0f                    // fp32(48000*0.45), exact
constexpr float  TWO_PI_F  = 6.283185307179586476925286766559f;  // 0x40C90FDB
constexpr double INV_2PI_D = 0.15915494309189533576888376337251;
constexpr float  RC1 = (float)INV_2PI_D;
constexpr float  RC2 = (float)(INV_2PI_D - (double)RC1);
constexpr double INV_SR_D = 1.0 / 48000.0;
constexpr float  DD1 = (float)INV_SR_D;
constexpr float  DD2 = (float)(INV_SR_D - (double)DD1);

__device__ __forceinline__ float hsin_rev(float r) {  // sin(2*pi*r)
#if __has_builtin(__builtin_amdgcn_sinf)
    return __builtin_amdgcn_sinf(r);                  // v_sin_f32: revolutions
#else
    return __sinf(r * TWO_PI_F);
#endif
}

// Correctly-rounded t/48000 via double-float mul (== IEEE f32 divide here;
// proved: no halfway cases, err 2^-47 << 2^-33.5 boundary distance).
__device__ __forceinline__ float div48000(float t) {
    float h = t * DD1;
    float r = __builtin_fmaf(t, DD1, -h);
    float s = __builtin_fmaf(t, DD2, r);
    return h + s;
}

// sin(ph) for f32 ph: double-float reduction to revolutions (|err|<=2^-25 rev)
__device__ __forceinline__ float sin_phase(float ph) {
    float h  = ph * RC1;
    float r  = __builtin_fmaf(ph, RC1, -h);
    float s  = __builtin_fmaf(ph, RC2, r);
    float nn = __builtin_rintf(h);
    float fr = (h - nn) + s;
    return hsin_rev(fr);
}

// kc[b,k] = fp32(k * fp32(sqrt(fp32(1 + fp32(inh*k^2)))))  -- np/jnp-exact
__device__ __forceinline__ float kcval(int k, float ib) {
    float kf = (float)(k + 1);
    float k2 = kf * kf;
    float m  = ib * k2;
    float s1 = 1.0f + m;
    float st = (float)sqrt((double)s1);
    return kf * st;
}

// ---- K1: f0_up[b,j], np-exact fp32 linear interp ---------------------------
__global__ void __launch_bounds__(256) k_f0up(const float* __restrict__ f0,
        float* __restrict__ f0up, int T, int n, float pf) {
    int j = blockIdx.x * 256 + threadIdx.x;
    int b = blockIdx.y;
    if (j >= n) return;
    float pos = ((float)j + 0.5f);
    pos = pos * pf;
    pos = pos - 0.5f;
    pos = fmaxf(pos, 0.0f);
    pos = fminf(pos, (float)(T - 1));
    int   i0 = (int)pos;
    int   i1 = min(i0 + 1, T - 1);
    float w  = pos - (float)i0;
    float omw = 1.0f - w;
    const float* fb = f0 + b * T;
    f0up[(size_t)b * n + j] = fb[i0] * omw + fb[i1] * w;
}

// ---- K2a: per (b,k) produce scan4 (level-4 inclusive tree scan) ------------
// No dynamically-indexed local arrays (they spill); scalar level geometry:
// len[l] = n>>l, off[l] = sum_{m=4}^{l-1} (n>>m).
__global__ void __launch_bounds__(256) k_scan4(const float* __restrict__ f0up,
        const float* __restrict__ inh, float* __restrict__ scan4,
        int N, int n) {
    __shared__ float lv[6016];
    const int k   = blockIdx.x;
    const int b   = blockIdx.y;
    const int tid = threadIdx.x;
    const float kc = kcval(k, inh[b]);
    const float4* f4 = (const float4*)(f0up + (size_t)b * n);
    const int len4 = n >> 4;

    // L4 from increments, prefetched one chunk ahead
    {
        int i = tid;
        float4 c0 = {}, c1 = {}, c2 = {}, c3 = {};
        if (i < len4) { c0 = f4[4*i]; c1 = f4[4*i+1]; c2 = f4[4*i+2]; c3 = f4[4*i+3]; }
        while (i < len4) {
            int ni = i + 256;
            float4 n0 = {}, n1 = {}, n2 = {}, n3 = {};
            if (ni < len4) { n0 = f4[4*ni]; n1 = f4[4*ni+1]; n2 = f4[4*ni+2]; n3 = f4[4*ni+3]; }
            float a0=div48000(TWO_PI_F*(kc*c0.x)), a1=div48000(TWO_PI_F*(kc*c0.y));
            float a2=div48000(TWO_PI_F*(kc*c0.z)), a3=div48000(TWO_PI_F*(kc*c0.w));
            float a4=div48000(TWO_PI_F*(kc*c1.x)), a5=div48000(TWO_PI_F*(kc*c1.y));
            float a6=div48000(TWO_PI_F*(kc*c1.z)), a7=div48000(TWO_PI_F*(kc*c1.w));
            float a8=div48000(TWO_PI_F*(kc*c2.x)), a9=div48000(TWO_PI_F*(kc*c2.y));
            float aA=div48000(TWO_PI_F*(kc*c2.z)), aB=div48000(TWO_PI_F*(kc*c2.w));
            float aC=div48000(TWO_PI_F*(kc*c3.x)), aD=div48000(TWO_PI_F*(kc*c3.y));
            float aE=div48000(TWO_PI_F*(kc*c3.z)), aF=div48000(TWO_PI_F*(kc*c3.w));
            float L2a=(a0+a1)+(a2+a3), L2b=(a4+a5)+(a6+a7);
            float L2c=(a8+a9)+(aA+aB), L2d=(aC+aD)+(aE+aF);
            lv[i] = (L2a+L2b) + (L2c+L2d);
            i = ni; c0 = n0; c1 = n1; c2 = n2; c3 = n3;
        }
    }
    __syncthreads();

    // upsweep
    int offp = 0, lenp = len4, P = 4;
    for (int l = 5; ; ++l) {
        int lenc = lenp >> 1;
        int offc = offp + lenp;
        for (int i = tid; i < lenc; i += 256)
            lv[offc + i] = lv[offp + 2*i] + lv[offp + 2*i + 1];
        __syncthreads();
        P = l;
        if (lenc == 1) break;
        offp = offc; lenp = lenc;
    }
    // downsweep (round-5-validated formulas)
    for (int l = P - 1; l >= 4; --l) {
        int lenl = n >> l;
        int offl = 0;
        for (int m = 4; m < l; ++m) offl += (n >> m);
        int offh = offl + lenl;
        int lenh = n >> (l + 1);
        float*       arr = lv + offl;
        const float* hi  = lv + offh;
        for (int i = tid; i < lenh; i += 256) {
            float v = hi[i];
            int e = 2*i + 2;
            if (e < lenl) arr[e] = v + arr[e];
            arr[2*i + 1] = v;
        }
        __syncthreads();
    }
    float* sp = scan4 + (size_t)(b * N + k) * len4;
    for (int i = tid; i < len4; i += 256) sp[i] = lv[i];
}

// ---- K2b: 16 consecutive j per thread, uniform reconstruction from scan4 ---
#define ROWS 26
__global__ void __launch_bounds__(256, 4) k_synth3(
        const float* __restrict__ harm, const float* __restrict__ f0up,
        const float* __restrict__ inh,  const float* __restrict__ scan4,
        float* __restrict__ out, int B, int T, int N, int n, float pf, int kpg) {
    const int tid  = threadIdx.x;
    const int b    = blockIdx.y;
    const int k0   = blockIdx.z * kpg;
    const int q    = blockIdx.x * 256 + tid;      // 16-sample group id
    const int NG   = n >> 4;
    const int kend = min(k0 + kpg, N);
    const int kact = kend - k0;

    __shared__ float2 amps[ROWS * 32];            // (row r, row r+1) x k
    __shared__ float  kcs[32];

    const float ib    = inh[b];
    const float tmaxf = (float)(T - 1);

    for (int i = tid; i < kact; i += 256) kcs[i] = kcval(k0 + i, ib);

    const int j0blk = blockIdx.x * 4096;
    int i0min;
    {
        float p = ((float)j0blk + 0.5f);
        p = p * pf; p = p - 0.5f;
        p = fmaxf(p, 0.0f); p = fminf(p, tmaxf);
        i0min = (int)p;
    }
    for (int idx = tid; idx < ROWS * kact; idx += 256) {
        int r = idx / kact, kk = idx - r * kact;
        int r0 = min(i0min + r, T - 1);
        int r1 = min(i0min + r + 1, T - 1);
        amps[idx] = make_float2(harm[((size_t)b * T + r0) * N + (k0 + kk)],
                                harm[((size_t)b * T + r1) * N + (k0 + kk)]);
    }
    __syncthreads();                              // last barrier

    float u[16], w[16];
    int   ao[16];
    float um = __builtin_inff();
    if (q < NG) {
        const float4* up = (const float4*)(f0up + (size_t)b * n + (size_t)q * 16);
        float4 v0 = up[0], v1 = up[1], v2 = up[2], v3 = up[3];
        u[0]=v0.x; u[1]=v0.y; u[2]=v0.z; u[3]=v0.w;
        u[4]=v1.x; u[5]=v1.y; u[6]=v1.z; u[7]=v1.w;
        u[8]=v2.x; u[9]=v2.y; u[10]=v2.z; u[11]=v2.w;
        u[12]=v3.x; u[13]=v3.y; u[14]=v3.z; u[15]=v3.w;
        #pragma unroll
        for (int i = 0; i < 16; ++i) {
            um = fminf(um, u[i]);
            int j = q * 16 + i;
            float p = ((float)j + 0.5f);
            p = p * pf; p = p - 0.5f;
            p = fmaxf(p, 0.0f); p = fminf(p, tmaxf);
            int i0 = (int)p;
            w[i]  = p - (float)i0;
            ao[i] = (i0 - i0min) * kact;
        }
    }
    // per-wave min (finer early-exit than block min; no barriers)
    #pragma unroll
    for (int off = 32; off > 0; off >>= 1)
        um = fminf(um, __shfl_xor(um, off));
    const float umin = um;

    if (q < NG) {
        float acc[16];
        #pragma unroll
        for (int i = 0; i < 16; ++i) acc[i] = 0.0f;

        const float* s4k = scan4 + (size_t)(b * N + k0) * NG;
        float g0c = (q == 0) ? 0.0f : s4k[q - 1];
        float g1c = s4k[q];

        for (int k = k0; k < kend; ++k) {
            const int   kk = k - k0;
            const float kc = kcs[kk];
            if (kc * umin >= NYQF) break;         // wave-uniform; kc monotone
            const float g0 = g0c, g1 = g1c;
            if (k + 1 < kend) {                   // prefetch next k row
                const float* nx = s4k + NG;
                g0c = (q == 0) ? 0.0f : nx[q - 1];
                g1c = nx[q];
                s4k = nx;
            }

            float x[16];
            #pragma unroll
            for (int i = 0; i < 16; ++i)
                x[i] = div48000(TWO_PI_F * (kc * u[i]));

            // tree partials (round-5-validated associations)
            float L1a = x[0]+x[1],   L1b = x[2]+x[3];
            float L1c = x[4]+x[5],   L1d = x[6]+x[7];
            float L1e = x[8]+x[9],   L1f = x[10]+x[11];
            float L1g = x[12]+x[13];
            float L2a = L1a+L1b, L2b = L1c+L1d, L2c = L1e+L1f;
            float L3a = L2a+L2b;
            float p0  = g0 + x[0];
            float s10 = g0 + L1a;
            float p2  = s10 + x[2];
            float s20 = g0 + L2a;
            float p4  = s20 + x[4];
            float s12 = s20 + L1c;
            float p6  = s12 + x[6];
            float s3v = g0 + L3a;
            float p8  = s3v + x[8];
            float s14 = s3v + L1e;
            float p10 = s14 + x[10];
            float s22 = s3v + L2c;
            float p12 = s22 + x[12];
            float s16 = s22 + L1g;
            float p14 = s16 + x[14];

            auto emit = [&](int i, float ph) {
                float t1 = kc * u[i];             // same RN product as ref mask
                if (t1 < NYQF) {
                    float  sv  = sin_phase(ph);
                    float2 a01 = amps[ao[i] + kk];
                    float  wv  = w[i];
                    float  a   = a01.x * (1.0f - wv) + a01.y * wv;
                    acc[i] += a * sv;
                }
            };
            emit(0, p0);   emit(1, s10);  emit(2, p2);   emit(3, s20);
            emit(4, p4);   emit(5, s12);  emit(6, p6);   emit(7, s3v);
            emit(8, p8);   emit(9, s14);  emit(10, p10); emit(11, s22);
            emit(12, p12); emit(13, s16); emit(14, p14); emit(15, g1);
        }

        const float Nf = (float)N;
        float* ob = out + (size_t)b * n + (size_t)q * 16;
        #pragma unroll
        for (int i = 0; i < 16; ++i) atomicAdd(&ob[i], acc[i] / Nf);
    }
}

// ---- Fallback: round-5 proven kernel (atomics, 96 KB LDS) ------------------
__global__ void __launch_bounds__(256) k_scan_synth(
        const float* __restrict__ harm, const float* __restrict__ f0up,
        const float* __restrict__ inh,  float* __restrict__ out,
        int B, int T, int N, int n, float pf) {
    extern __shared__ float lv[];
    const int k   = blockIdx.x;
    const int b   = blockIdx.y;
    const int tid = threadIdx.x;
    const float kc = kcval(k, inh[b]);
    const float* fb = f0up + (size_t)b * n;

    auto inc = [&](int j) -> float {
        float u    = fb[j];
        float inst = kc * u;
        float tt   = TWO_PI_F * inst;
        return tt / SRF;
    };

    const int len1 = n >> 1;
    {
        const float4* f4 = (const float4*)fb;
        for (int i = tid; i < (n >> 2); i += 256) {
            float4 u = f4[i];
            float a0 = (TWO_PI_F * (kc * u.x)) / SRF;
            float a1 = (TWO_PI_F * (kc * u.y)) / SRF;
            float a2 = (TWO_PI_F * (kc * u.z)) / SRF;
            float a3 = (TWO_PI_F * (kc * u.w)) / SRF;
            lv[i] = (a0 + a1) + (a2 + a3);
        }
    }
    __syncthreads();
    int offp = 0, lenp = n >> 2, P = 2;
    for (int l = 3; ; ++l) {
        int lenc = lenp >> 1;
        int offc = offp + lenp;
        for (int i = tid; i < lenc; i += 256)
            lv[offc + i] = lv[offp + 2*i] + lv[offp + 2*i + 1];
        __syncthreads();
        P = l;
        if (lenc == 1) break;
        offp = offc; lenp = lenc;
    }
    for (int l = P - 1; l >= 2; --l) {
        int lenl = n >> l;
        int offl = 0;
        for (int m = 2; m < l; ++m) offl += (n >> m);
        float*       arr = lv + offl;
        const float* hi  = lv + offl + lenl;
        int lenh = n >> (l + 1);
        for (int i = tid; i < lenh; i += 256) {
            float v = hi[i];
            int e = 2*i + 2;
            if (e < lenl) arr[e] = v + arr[e];
            arr[2*i + 1] = v;
        }
        __syncthreads();
    }
    const float* scan2 = lv;

    const float  tmaxf = (float)(T - 1);
    const float  invN  = 1.0f / (float)N;
    const float* hb    = harm + (size_t)b * T * N + k;
    float*       ob    = out + (size_t)b * n;

    auto emit = [&](int j, float ph) {
        float u    = fb[j];
        float inst = kc * u;
        if (!(inst < NYQF)) return;
        double pr = (double)ph * INV_2PI_D;
        double fr = pr - rint(pr);
        float  sv = hsin_rev((float)fr);
        float pos = ((float)j + 0.5f);
        pos = pos * pf; pos = pos - 0.5f;
        pos = fmaxf(pos, 0.0f); pos = fminf(pos, tmaxf);
        int   i0 = (int)pos;
        int   i1 = min(i0 + 1, T - 1);
        float w  = pos - (float)i0;
        float a  = hb[(size_t)i0 * N] * (1.0f - w) + hb[(size_t)i1 * N] * w;
        atomicAdd(&ob[j], (a * sv) * invN);
    };

    if (tid == 0) emit(0, inc(0));
    for (int tt = tid; tt < len1; tt += 256) {
        float s1;
        if (tt == 0)      s1 = inc(0) + inc(1);
        else if (tt & 1)  s1 = scan2[(tt - 1) >> 1];
        else              s1 = scan2[(tt >> 1) - 1] + (inc(2*tt) + inc(2*tt + 1));
        emit(2*tt + 1, s1);
        int je = 2*tt + 2;
        if (je < n) emit(je, s1 + inc(je));
    }
}

extern "C" void kernel_launch(void* const* d_in, const int* in_sizes, int n_in,
                              void* d_out, int out_size, void* d_ws, size_t ws_size,
                              hipStream_t stream) {
    const int B = in_sizes[2];                 // 16
    const int T = in_sizes[1] / B;             // 250
    const int N = in_sizes[0] / (B * T);       // 100
    const int n = out_size / B;                // 48000
    const float pf = (float)((double)T / (double)n);

    const float* harm = (const float*)d_in[0];
    const float* f0   = (const float*)d_in[1];
    const float* inh  = (const float*)d_in[2];
    float* out  = (float*)d_out;
    float* f0up = (float*)d_ws;                // B*n floats = 3.07 MB

    const int KZ  = 4;
    const int kpg = (N + KZ - 1) / KZ;         // 25
    const size_t needFast = (size_t)B * n * 4 + (size_t)B * N * (n / 16) * 4;
    const bool fast = (ws_size >= needFast) && (n % 16 == 0) && (kpg <= 32);

    k_f0up<<<dim3((n + 255) / 256, B), 256, 0, stream>>>(f0, f0up, T, n, pf);
    hipMemsetAsync(d_out, 0, (size_t)out_size * sizeof(float), stream);

    if (fast) {
        float* scan4 = (float*)((char*)d_ws + (size_t)B * n * 4);
        k_scan4<<<dim3(N, B), 256, 0, stream>>>(f0up, inh, scan4, N, n);
        const int NG    = n / 16;                          // 3000
        const int tiles = (NG + 255) / 256;                // 12
        k_synth3<<<dim3(tiles, B, KZ), 256, 0, stream>>>(
            harm, f0up, inh, scan4, out, B, T, N, n, pf, kpg);
    } else {
        const size_t lds_bytes = (size_t)(n / 2) * sizeof(float);  // 96 KB
        k_scan_synth<<<dim3(N, B), 256, lds_bytes, stream>>>(
            harm, f0up, inh, out, B, T, N, n, pf);
    }
}